// Round 9
// baseline (1257.314 us; speedup 1.0000x reference)
//
#include <hip/hip_runtime.h>
#include <math.h>

// Problem constants
#define NB 8
#define NS 2048
#define ND 1024
#define NK 4096
#define NM (NB * NS)      // 16384 tokens

#define BM 128
#define BN 128
#define BK 32
#define NT (ND / BK)      // 32 K-tiles (BK=32 variants)
#define NTILES (NK / BN)  // 32

typedef __attribute__((ext_vector_type(8))) short bf8_t;
typedef __attribute__((ext_vector_type(4))) float f4_t;
typedef __attribute__((ext_vector_type(8))) unsigned short us8_t;
typedef __attribute__((ext_vector_type(4))) unsigned int u4_t;

#define GLOBAL_AS(p) ((const __attribute__((address_space(1))) void*)(p))
#define LDS_AS(p)    ((__attribute__((address_space(3))) void*)(p))

struct Top2 { float m1; int i1; float m2; int i2; };

__device__ __forceinline__ void top2_push(float m, int i,
                                          float& m1, int& i1, float& m2, int& i2) {
  if (m < m1 || (m == m1 && i < i1)) { m2 = m1; i2 = i1; m1 = m; i1 = i; }
  else if (m < m2 || (m == m2 && i < i2)) { m2 = m; i2 = i; }
}

__device__ __forceinline__ unsigned short f2bf(float f) {
  unsigned u = __float_as_uint(f);
  u += 0x7fffu + ((u >> 16) & 1u);
  return (unsigned short)(u >> 16);
}

// ---------------------------------------------------------------------------
// Kernel 0: fp32 -> bf16 conversion
// ---------------------------------------------------------------------------
__global__ void vq_convert(const float* __restrict__ x, const float* __restrict__ cb,
                           unsigned short* __restrict__ xb, unsigned short* __restrict__ cbb) {
  const int xg = NM * ND / 8;
  const int total = xg + NK * ND / 8;
  for (int g = blockIdx.x * blockDim.x + threadIdx.x; g < total;
       g += gridDim.x * blockDim.x) {
    const float* src; unsigned short* dst; size_t off;
    if (g < xg) { src = x; dst = xb; off = (size_t)g * 8; }
    else        { src = cb; dst = cbb; off = (size_t)(g - xg) * 8; }
    float4 a = *reinterpret_cast<const float4*>(src + off);
    float4 b = *reinterpret_cast<const float4*>(src + off + 4);
    us8_t o;
    o[0] = f2bf(a.x); o[1] = f2bf(a.y); o[2] = f2bf(a.z); o[3] = f2bf(a.w);
    o[4] = f2bf(b.x); o[5] = f2bf(b.y); o[6] = f2bf(b.z); o[7] = f2bf(b.w);
    *reinterpret_cast<us8_t*>(dst + off) = o;
  }
}

// ---------------------------------------------------------------------------
// Kernel 1: codebook squared norms (fp64 accumulate, exact)
// ---------------------------------------------------------------------------
__global__ void vq_cnorm(const float* __restrict__ cb, float* __restrict__ cnorm) {
  const int lane = threadIdx.x & 63;
  const int code = blockIdx.x * 4 + (threadIdx.x >> 6);
  const float* c = cb + (size_t)code * ND;
  double s = 0.0;
#pragma unroll
  for (int j = 0; j < ND / 64; ++j) {
    double v = (double)c[lane + 64 * j];
    s = fma(v, v, s);
  }
#pragma unroll
  for (int off = 32; off > 0; off >>= 1) s += __shfl_down(s, off, 64);
  if (lane == 0) cnorm[code] = (float)s;
}

// ---------------------------------------------------------------------------
// Shared epilogue: score = cnorm - 2*acc -> per-token top2 -> part[]
// ---------------------------------------------------------------------------
__device__ __forceinline__ void dist_epilogue(f4_t (&acc)[4][4], const float* __restrict__ cnorm,
                                              Top2 (*Ep)[2], Top2* __restrict__ part,
                                              int m0, int n0, int tid, int wr, int wc,
                                              int lo, int hi, int bx) {
  float cn[4];
#pragma unroll
  for (int n = 0; n < 4; ++n) cn[n] = cnorm[n0 + wc * 64 + n * 16 + lo];
#pragma unroll
  for (int m = 0; m < 4; ++m) {
#pragma unroll
    for (int j = 0; j < 4; ++j) {
      float m1 = INFINITY, m2 = INFINITY; int i1 = 0x7fffffff, i2 = 0x7fffffff;
#pragma unroll
      for (int n = 0; n < 4; ++n) {
        float s = fmaf(-2.f, acc[m][n][j], cn[n]);
        top2_push(s, n0 + wc * 64 + n * 16 + lo, m1, i1, m2, i2);
      }
#pragma unroll
      for (int mask = 1; mask <= 8; mask <<= 1) {
        float om1 = __shfl_xor(m1, mask, 64); int oi1 = __shfl_xor(i1, mask, 64);
        float om2 = __shfl_xor(m2, mask, 64); int oi2 = __shfl_xor(i2, mask, 64);
        top2_push(om1, oi1, m1, i1, m2, i2);
        top2_push(om2, oi2, m1, i1, m2, i2);
      }
      if (lo == 0) {
        int row = wr * 64 + m * 16 + hi * 4 + j;
        Top2 e; e.m1 = m1; e.i1 = i1; e.m2 = m2; e.i2 = i2;
        Ep[row][wc] = e;
      }
    }
  }
  __syncthreads();
  if (tid < BM) {
    Top2 a = Ep[tid][0], b = Ep[tid][1];
    float m1 = a.m1, m2 = a.m2; int i1 = a.i1, i2 = a.i2;
    top2_push(b.m1, b.i1, m1, i1, m2, i2);
    top2_push(b.m2, b.i2, m1, i1, m2, i2);
    Top2 r; r.m1 = m1; r.i1 = i1; r.m2 = m2; r.i2 = i2;
    part[(size_t)(m0 + tid) * NTILES + bx] = r;
  }
}

// ---------------------------------------------------------------------------
// V0 (SWZ=0): R7 control — gload_lds, depth-2 prefetch, counted vmcnt.
// V3 (SWZ=1): + T2 XOR swizzle (chunk ^= (row>>1)&3, source+read both sides).
// ---------------------------------------------------------------------------
template <int SWZ>
__global__ void __launch_bounds__(256)
vq_dist_v0(const unsigned short* __restrict__ xb, const unsigned short* __restrict__ cbb,
           const float* __restrict__ cnorm, Top2* __restrict__ part, int moff) {
  __shared__ __align__(16) char smem[49152];
  Top2 (*Ep)[2] = reinterpret_cast<Top2 (*)[2]>(smem);

  const int tid = threadIdx.x, lane = tid & 63, wid = tid >> 6;
  const int wr = wid >> 1, wc = wid & 1, lo = lane & 15, hi = lane >> 4;
  const int m0 = moff + blockIdx.y * BM, n0 = blockIdx.x * BN;

  // stage source: lane l -> row l>>2, chunk cg (swizzled for SWZ=1; LDS dest linear)
  const int cg = SWZ ? ((lane & 3) ^ ((lane >> 3) & 3)) : (lane & 3);
  const unsigned short* aSrc = xb + (size_t)(m0 + wid * 32 + (lane >> 2)) * ND + cg * 8;
  const unsigned short* bSrc = cbb + (size_t)(n0 + wid * 32 + (lane >> 2)) * ND + cg * 8;

#define STAGE(buf, tile) do {                                                        \
    char* aD_ = smem + (buf) * 16384 + wid * 2048;                                   \
    char* bD_ = smem + (buf) * 16384 + 8192 + wid * 2048;                            \
    const int k0_ = (tile) * BK;                                                     \
    __builtin_amdgcn_global_load_lds(GLOBAL_AS(aSrc + k0_), LDS_AS(aD_), 16, 0, 0);  \
    __builtin_amdgcn_global_load_lds(GLOBAL_AS(aSrc + k0_ + 16 * ND), LDS_AS(aD_ + 1024), 16, 0, 0); \
    __builtin_amdgcn_global_load_lds(GLOBAL_AS(bSrc + k0_), LDS_AS(bD_), 16, 0, 0);  \
    __builtin_amdgcn_global_load_lds(GLOBAL_AS(bSrc + k0_ + 16 * ND), LDS_AS(bD_ + 1024), 16, 0, 0); \
  } while (0)

  f4_t acc[4][4];
#pragma unroll
  for (int m = 0; m < 4; ++m)
#pragma unroll
    for (int n = 0; n < 4; ++n) acc[m][n] = (f4_t)0.f;

  STAGE(0, 0);
  STAGE(1, 1);
  asm volatile("s_waitcnt vmcnt(4)" ::: "memory");
  __builtin_amdgcn_s_barrier();

  const int rchunk = SWZ ? (hi ^ ((lo >> 1) & 3)) : hi;
  for (int t = 0; t < NT; ++t) {
    const int cur = t % 3;
    if (t + 2 < NT) STAGE((t + 2) % 3, t + 2);

    const char* aRd = smem + cur * 16384 + (wr * 64 + lo) * 64 + rchunk * 16;
    const char* bRd = smem + cur * 16384 + 8192 + (wc * 64 + lo) * 64 + rchunk * 16;
    bf8_t af[4], bfr[4];
#pragma unroll
    for (int m = 0; m < 4; ++m) af[m] = *reinterpret_cast<const bf8_t*>(aRd + m * 1024);
#pragma unroll
    for (int n = 0; n < 4; ++n) bfr[n] = *reinterpret_cast<const bf8_t*>(bRd + n * 1024);
#pragma unroll
    for (int m = 0; m < 4; ++m)
#pragma unroll
      for (int n = 0; n < 4; ++n)
        acc[m][n] = __builtin_amdgcn_mfma_f32_16x16x32_bf16(af[m], bfr[n], acc[m][n], 0, 0, 0);

    if (t + 2 < NT) asm volatile("s_waitcnt vmcnt(4)" ::: "memory");
    else            asm volatile("s_waitcnt vmcnt(0)" ::: "memory");
    __builtin_amdgcn_s_barrier();
  }
#undef STAGE

  dist_epilogue(acc, cnorm, Ep, part, m0, n0, tid, wr, wc, lo, hi, blockIdx.x);
}

// ---------------------------------------------------------------------------
// V1: reg-staging (global->VGPR->ds_write), T14 issue-early/write-late,
// raw barrier with lgkmcnt(0) only (global loads stay in flight).
// ---------------------------------------------------------------------------
__global__ void __launch_bounds__(256)
vq_dist_reg(const unsigned short* __restrict__ xb, const unsigned short* __restrict__ cbb,
            const float* __restrict__ cnorm, Top2* __restrict__ part, int moff) {
  __shared__ __align__(16) char smem[32768];   // 2 bufs x (A 8KB + B 8KB)
  Top2 (*Ep)[2] = reinterpret_cast<Top2 (*)[2]>(smem);

  const int tid = threadIdx.x, lane = tid & 63, wid = tid >> 6;
  const int wr = wid >> 1, wc = wid & 1, lo = lane & 15, hi = lane >> 4;
  const int m0 = moff + blockIdx.y * BM, n0 = blockIdx.x * BN;

  const unsigned short* aS = xb + (size_t)(m0 + wid * 32 + (lane >> 2)) * ND + (lane & 3) * 8;
  const unsigned short* bS = cbb + (size_t)(n0 + wid * 32 + (lane >> 2)) * ND + (lane & 3) * 8;
  char* aW = smem + wid * 2048 + lane * 16;

  u4_t ra0, ra1, rb0, rb1;
#define LOADREG(t) do { const int k0_ = (t) * BK;                            \
    ra0 = *reinterpret_cast<const u4_t*>(aS + k0_);                          \
    ra1 = *reinterpret_cast<const u4_t*>(aS + k0_ + 16 * ND);                \
    rb0 = *reinterpret_cast<const u4_t*>(bS + k0_);                          \
    rb1 = *reinterpret_cast<const u4_t*>(bS + k0_ + 16 * ND); } while (0)
#define WRITEREG(buf) do { char* w_ = aW + (buf) * 16384;                    \
    *reinterpret_cast<u4_t*>(w_) = ra0;                                      \
    *reinterpret_cast<u4_t*>(w_ + 1024) = ra1;                               \
    *reinterpret_cast<u4_t*>(w_ + 8192) = rb0;                               \
    *reinterpret_cast<u4_t*>(w_ + 8192 + 1024) = rb1; } while (0)

  f4_t acc[4][4];
#pragma unroll
  for (int m = 0; m < 4; ++m)
#pragma unroll
    for (int n = 0; n < 4; ++n) acc[m][n] = (f4_t)0.f;

  LOADREG(0);
  WRITEREG(0);
  LOADREG(1);
  asm volatile("s_waitcnt lgkmcnt(0)" ::: "memory");
  __builtin_amdgcn_s_barrier();

  for (int t = 0; t < NT; ++t) {
    const int cur = t & 1;
    const char* aRd = smem + cur * 16384 + (wr * 64 + lo) * 64 + hi * 16;
    const char* bRd = smem + cur * 16384 + 8192 + (wc * 64 + lo) * 64 + hi * 16;
    bf8_t af[4], bfr[4];
#pragma unroll
    for (int m = 0; m < 4; ++m) af[m] = *reinterpret_cast<const bf8_t*>(aRd + m * 1024);
#pragma unroll
    for (int n = 0; n < 4; ++n) bfr[n] = *reinterpret_cast<const bf8_t*>(bRd + n * 1024);
#pragma unroll
    for (int m = 0; m < 4; ++m)
#pragma unroll
      for (int n = 0; n < 4; ++n)
        acc[m][n] = __builtin_amdgcn_mfma_f32_16x16x32_bf16(af[m], bfr[n], acc[m][n], 0, 0, 0);

    if (t + 1 < NT) {
      WRITEREG(cur ^ 1);                 // compiler waits vmcnt for t+1's regs here
      if (t + 2 < NT) LOADREG(t + 2);    // issue early; in flight across barrier
    }
    asm volatile("s_waitcnt lgkmcnt(0)" ::: "memory");
    __builtin_amdgcn_s_barrier();
  }
#undef LOADREG
#undef WRITEREG

  dist_epilogue(acc, cnorm, Ep, part, m0, n0, tid, wr, wc, lo, hi, blockIdx.x);
}

// ---------------------------------------------------------------------------
// V2: BK=64, double-buffered gload_lds (16 fat steps), LDS stored as two
// stacked [128][32] k-halves so the read pattern matches V0.
// ---------------------------------------------------------------------------
__global__ void __launch_bounds__(256)
vq_dist_bk64(const unsigned short* __restrict__ xb, const unsigned short* __restrict__ cbb,
             const float* __restrict__ cnorm, Top2* __restrict__ part, int moff) {
  __shared__ __align__(16) char smem[65536];   // 2 bufs x 32KB
  Top2 (*Ep)[2] = reinterpret_cast<Top2 (*)[2]>(smem);

  const int tid = threadIdx.x, lane = tid & 63, wid = tid >> 6;
  const int wr = wid >> 1, wc = wid & 1, lo = lane & 15, hi = lane >> 4;
  const int m0 = moff + blockIdx.y * BM, n0 = blockIdx.x * BN;

  const unsigned short* aSrc = xb + (size_t)(m0 + wid * 32 + (lane >> 2)) * ND + (lane & 3) * 8;
  const unsigned short* bSrc = cbb + (size_t)(n0 + wid * 32 + (lane >> 2)) * ND + (lane & 3) * 8;

#define STAGE64(buf, tile) do {                                                       \
    char* base_ = smem + (buf) * 32768;                                               \
    const int k0_ = (tile) * 64;                                                      \
    _Pragma("unroll")                                                                 \
    for (int h_ = 0; h_ < 2; ++h_) {                                                  \
      char* aD_ = base_ + h_ * 8192 + wid * 2048;                                     \
      char* bD_ = base_ + 16384 + h_ * 8192 + wid * 2048;                             \
      __builtin_amdgcn_global_load_lds(GLOBAL_AS(aSrc + k0_ + h_ * 32), LDS_AS(aD_), 16, 0, 0); \
      __builtin_amdgcn_global_load_lds(GLOBAL_AS(aSrc + k0_ + h_ * 32 + 16 * ND), LDS_AS(aD_ + 1024), 16, 0, 0); \
      __builtin_amdgcn_global_load_lds(GLOBAL_AS(bSrc + k0_ + h_ * 32), LDS_AS(bD_), 16, 0, 0); \
      __builtin_amdgcn_global_load_lds(GLOBAL_AS(bSrc + k0_ + h_ * 32 + 16 * ND), LDS_AS(bD_ + 1024), 16, 0, 0); \
    } } while (0)

  f4_t acc[4][4];
#pragma unroll
  for (int m = 0; m < 4; ++m)
#pragma unroll
    for (int n = 0; n < 4; ++n) acc[m][n] = (f4_t)0.f;

  STAGE64(0, 0);
  asm volatile("s_waitcnt vmcnt(0)" ::: "memory");
  __builtin_amdgcn_s_barrier();

  const int NT64 = ND / 64;   // 16
  for (int t = 0; t < NT64; ++t) {
    if (t + 1 < NT64) STAGE64((t + 1) & 1, t + 1);
    const char* base = smem + (t & 1) * 32768;
#pragma unroll
    for (int h = 0; h < 2; ++h) {
      const char* aRd = base + h * 8192 + (wr * 64 + lo) * 64 + hi * 16;
      const char* bRd = base + 16384 + h * 8192 + (wc * 64 + lo) * 64 + hi * 16;
      bf8_t af[4], bfr[4];
#pragma unroll
      for (int m = 0; m < 4; ++m) af[m] = *reinterpret_cast<const bf8_t*>(aRd + m * 1024);
#pragma unroll
      for (int n = 0; n < 4; ++n) bfr[n] = *reinterpret_cast<const bf8_t*>(bRd + n * 1024);
#pragma unroll
      for (int m = 0; m < 4; ++m)
#pragma unroll
        for (int n = 0; n < 4; ++n)
          acc[m][n] = __builtin_amdgcn_mfma_f32_16x16x32_bf16(af[m], bfr[n], acc[m][n], 0, 0, 0);
    }
    asm volatile("s_waitcnt vmcnt(0)" ::: "memory");
    __builtin_amdgcn_s_barrier();
  }
#undef STAGE64

  dist_epilogue(acc, cnorm, Ep, part, m0, n0, tid, wr, wc, lo, hi, blockIdx.x);
}

// ---------------------------------------------------------------------------
// Kernel 3: merge partials -> top-4 -> fp64-exact refine -> gather + PE
// ---------------------------------------------------------------------------
__device__ __forceinline__ void ins4(float m, int i, float v[4], int ix[4]) {
  if (!(m < v[3] || (m == v[3] && i < ix[3]))) return;
  v[3] = m; ix[3] = i;
  if (v[3] < v[2] || (v[3] == v[2] && ix[3] < ix[2])) {
    float tv = v[2]; v[2] = v[3]; v[3] = tv; int ti = ix[2]; ix[2] = ix[3]; ix[3] = ti;
  }
  if (v[2] < v[1] || (v[2] == v[1] && ix[2] < ix[1])) {
    float tv = v[1]; v[1] = v[2]; v[2] = tv; int ti = ix[1]; ix[1] = ix[2]; ix[2] = ti;
  }
  if (v[1] < v[0] || (v[1] == v[0] && ix[1] < ix[0])) {
    float tv = v[0]; v[0] = v[1]; v[1] = tv; int ti = ix[0]; ix[0] = ix[1]; ix[1] = ti;
  }
}

__global__ void vq_finalize(const float* __restrict__ x, const float* __restrict__ cb,
                            const Top2* __restrict__ part, float* __restrict__ out) {
  const int t = blockIdx.x;
  const int s = t & (NS - 1);
  const int tid = threadIdx.x;
  const int lane = tid & 63;
  const int wav = tid >> 6;

  __shared__ int candS[4];
  __shared__ double dS[4];
  __shared__ int selS;

  if (wav == 0) {
    float v[4] = {INFINITY, INFINITY, INFINITY, INFINITY};
    int ix[4] = {0x7fffffff, 0x7fffffff, 0x7fffffff, 0x7fffffff};
    if (lane < NTILES) {
      Top2 e = part[(size_t)t * NTILES + lane];
      v[0] = e.m1; ix[0] = e.i1; v[1] = e.m2; ix[1] = e.i2;
    }
#pragma unroll
    for (int mask = 1; mask <= 16; mask <<= 1) {
      float ov[4]; int oi[4];
#pragma unroll
      for (int p = 0; p < 4; ++p) { ov[p] = __shfl_xor(v[p], mask, 64); oi[p] = __shfl_xor(ix[p], mask, 64); }
#pragma unroll
      for (int p = 0; p < 4; ++p) ins4(ov[p], oi[p], v, ix);
    }
    if (lane < 4) candS[lane] = ix[lane];
  }
  __syncthreads();

  const int ci = candS[wav];
  const float* xt = x + (size_t)t * ND;
  const float* c = cb + (size_t)ci * ND;
  double d = 0.0;
#pragma unroll
  for (int r = 0; r < ND / 64; ++r) {
    int j = lane + 64 * r;
    double a = (double)xt[j] - (double)c[j];
    d = fma(a, a, d);
  }
#pragma unroll
  for (int off = 32; off > 0; off >>= 1) d += __shfl_down(d, off, 64);
  if (lane == 0) dS[wav] = d;
  __syncthreads();

  if (tid == 0) {
    double bd = dS[0]; int bi = candS[0];
#pragma unroll
    for (int w = 1; w < 4; ++w) {
      if (dS[w] < bd || (dS[w] == bd && candS[w] < bi)) { bd = dS[w]; bi = candS[w]; }
    }
    selS = bi;
  }
  __syncthreads();
  const int sel = selS;

  const float coef = (float)(9.210340371976184 / 1024.0);
  const float* cs = cb + (size_t)sel * ND;
  float* ot = out + (size_t)t * ND;
  const float sf = (float)s;
#pragma unroll
  for (int r = 0; r < ND / 256; ++r) {
    int j = tid + 256 * r;
    int iv = j & ~1;
    float div = expf(-(float)iv * coef);
    float ang = sf * div;
    float pe = (j & 1) ? cosf(ang) : sinf(ang);
    ot[j] = cs[j] + pe;
  }
}

// ---------------------------------------------------------------------------
extern "C" void kernel_launch(void* const* d_in, const int* in_sizes, int n_in,
                              void* d_out, int out_size, void* d_ws, size_t ws_size,
                              hipStream_t stream) {
  const float* x = (const float*)d_in[0];
  const float* cb = (const float*)d_in[1];
  float* out = (float*)d_out;

  unsigned short* xb = (unsigned short*)d_ws;
  unsigned short* cbb = (unsigned short*)((char*)d_ws + (size_t)NM * ND * 2);
  float* cnorm = (float*)((char*)d_ws + (size_t)NM * ND * 2 + (size_t)NK * ND * 2);
  Top2* part = (Top2*)((char*)cnorm + 16384);

  vq_convert<<<2048, 256, 0, stream>>>(x, cb, xb, cbb);
  vq_cnorm<<<NK / 4, 256, 0, stream>>>(cb, cnorm);

  // 4-way ablation: each variant computes a disjoint 4096-token M-slice
  dim3 g(NTILES, NM / BM / 4);  // (32, 32)
  vq_dist_v0<0><<<g, 256, 0, stream>>>(xb, cbb, cnorm, part, 0);       // control
  vq_dist_reg<<<g, 256, 0, stream>>>(xb, cbb, cnorm, part, 4096);      // reg-staging T14
  vq_dist_bk64<<<g, 256, 0, stream>>>(xb, cbb, cnorm, part, 8192);     // BK=64 fat steps
  vq_dist_v0<1><<<g, 256, 0, stream>>>(xb, cbb, cnorm, part, 12288);   // + T2 swizzle

  vq_finalize<<<NM, 256, 0, stream>>>(x, cb, part, out);
}

// Round 10
// 1214.900 us; speedup vs baseline: 1.0349x; 1.0349x over previous
//
#include <hip/hip_runtime.h>
#include <math.h>

// Problem constants
#define NB 8
#define NS 2048
#define ND 1024
#define NK 4096
#define NM (NB * NS)      // 16384 tokens

#define BM 128
#define BN 128
#define NTILES (NK / BN)  // 32

typedef __attribute__((ext_vector_type(8))) short bf8_t;
typedef __attribute__((ext_vector_type(4))) float f4_t;
typedef __attribute__((ext_vector_type(8))) unsigned short us8_t;

#define GLOBAL_AS(p) ((const __attribute__((address_space(1))) void*)(p))
#define LDS_AS(p)    ((__attribute__((address_space(3))) void*)(p))

struct Top2 { float m1; int i1; float m2; int i2; };

__device__ __forceinline__ void top2_push(float m, int i,
                                          float& m1, int& i1, float& m2, int& i2) {
  if (m < m1 || (m == m1 && i < i1)) { m2 = m1; i2 = i1; m1 = m; i1 = i; }
  else if (m < m2 || (m == m2 && i < i2)) { m2 = m; i2 = i; }
}

__device__ __forceinline__ unsigned short f2bf(float f) {
  unsigned u = __float_as_uint(f);
  u += 0x7fffu + ((u >> 16) & 1u);
  return (unsigned short)(u >> 16);
}

// ---------------------------------------------------------------------------
// Kernel 0: fp32 -> bf16 conversion
// ---------------------------------------------------------------------------
__global__ void vq_convert(const float* __restrict__ x, const float* __restrict__ cb,
                           unsigned short* __restrict__ xb, unsigned short* __restrict__ cbb) {
  const int xg = NM * ND / 8;
  const int total = xg + NK * ND / 8;
  for (int g = blockIdx.x * blockDim.x + threadIdx.x; g < total;
       g += gridDim.x * blockDim.x) {
    const float* src; unsigned short* dst; size_t off;
    if (g < xg) { src = x; dst = xb; off = (size_t)g * 8; }
    else        { src = cb; dst = cbb; off = (size_t)(g - xg) * 8; }
    float4 a = *reinterpret_cast<const float4*>(src + off);
    float4 b = *reinterpret_cast<const float4*>(src + off + 4);
    us8_t o;
    o[0] = f2bf(a.x); o[1] = f2bf(a.y); o[2] = f2bf(a.z); o[3] = f2bf(a.w);
    o[4] = f2bf(b.x); o[5] = f2bf(b.y); o[6] = f2bf(b.z); o[7] = f2bf(b.w);
    *reinterpret_cast<us8_t*>(dst + off) = o;
  }
}

// ---------------------------------------------------------------------------
// Kernel 1: codebook squared norms (fp64 accumulate, exact)
// ---------------------------------------------------------------------------
__global__ void vq_cnorm(const float* __restrict__ cb, float* __restrict__ cnorm) {
  const int lane = threadIdx.x & 63;
  const int code = blockIdx.x * 4 + (threadIdx.x >> 6);
  const float* c = cb + (size_t)code * ND;
  double s = 0.0;
#pragma unroll
  for (int j = 0; j < ND / 64; ++j) {
    double v = (double)c[lane + 64 * j];
    s = fma(v, v, s);
  }
#pragma unroll
  for (int off = 32; off > 0; off >>= 1) s += __shfl_down(s, off, 64);
  if (lane == 0) cnorm[code] = (float)s;
}

// ---------------------------------------------------------------------------
// Shared epilogue: score = cnorm - 2*acc -> per-token top2 -> part[]
// ---------------------------------------------------------------------------
__device__ __forceinline__ void dist_epilogue(f4_t (&acc)[4][4], const float* __restrict__ cnorm,
                                              Top2 (*Ep)[2], Top2* __restrict__ part,
                                              int m0, int n0, int tid, int wr, int wc,
                                              int lo, int hi, int bx) {
  float cn[4];
#pragma unroll
  for (int n = 0; n < 4; ++n) cn[n] = cnorm[n0 + wc * 64 + n * 16 + lo];
#pragma unroll
  for (int m = 0; m < 4; ++m) {
#pragma unroll
    for (int j = 0; j < 4; ++j) {
      float m1 = INFINITY, m2 = INFINITY; int i1 = 0x7fffffff, i2 = 0x7fffffff;
#pragma unroll
      for (int n = 0; n < 4; ++n) {
        float s = fmaf(-2.f, acc[m][n][j], cn[n]);
        top2_push(s, n0 + wc * 64 + n * 16 + lo, m1, i1, m2, i2);
      }
#pragma unroll
      for (int mask = 1; mask <= 8; mask <<= 1) {
        float om1 = __shfl_xor(m1, mask, 64); int oi1 = __shfl_xor(i1, mask, 64);
        float om2 = __shfl_xor(m2, mask, 64); int oi2 = __shfl_xor(i2, mask, 64);
        top2_push(om1, oi1, m1, i1, m2, i2);
        top2_push(om2, oi2, m1, i1, m2, i2);
      }
      if (lo == 0) {
        int row = wr * 64 + m * 16 + hi * 4 + j;
        Top2 e; e.m1 = m1; e.i1 = i1; e.m2 = m2; e.i2 = i2;
        Ep[row][wc] = e;
      }
    }
  }
  __syncthreads();
  if (tid < BM) {
    Top2 a = Ep[tid][0], b = Ep[tid][1];
    float m1 = a.m1, m2 = a.m2; int i1 = a.i1, i2 = a.i2;
    top2_push(b.m1, b.i1, m1, i1, m2, i2);
    top2_push(b.m2, b.i2, m1, i1, m2, i2);
    Top2 r; r.m1 = m1; r.i1 = i1; r.m2 = m2; r.i2 = i2;
    part[(size_t)(m0 + tid) * NTILES + bx] = r;
  }
}

// ---------------------------------------------------------------------------
// VA: BK=64 double-buffered gload_lds (16 fat steps) — R9's fastest variant.
// ---------------------------------------------------------------------------
__global__ void __launch_bounds__(256)
vq_dist_bk64(const unsigned short* __restrict__ xb, const unsigned short* __restrict__ cbb,
             const float* __restrict__ cnorm, Top2* __restrict__ part, int moff) {
  __shared__ __align__(16) char smem[65536];   // 2 bufs x 32KB
  Top2 (*Ep)[2] = reinterpret_cast<Top2 (*)[2]>(smem);

  const int tid = threadIdx.x, lane = tid & 63, wid = tid >> 6;
  const int wr = wid >> 1, wc = wid & 1, lo = lane & 15, hi = lane >> 4;
  const int m0 = moff + blockIdx.y * BM, n0 = blockIdx.x * BN;

  const unsigned short* aSrc = xb + (size_t)(m0 + wid * 32 + (lane >> 2)) * ND + (lane & 3) * 8;
  const unsigned short* bSrc = cbb + (size_t)(n0 + wid * 32 + (lane >> 2)) * ND + (lane & 3) * 8;

#define STAGE64(buf, tile) do {                                                       \
    char* base_ = smem + (buf) * 32768;                                               \
    const int k0_ = (tile) * 64;                                                      \
    _Pragma("unroll")                                                                 \
    for (int h_ = 0; h_ < 2; ++h_) {                                                  \
      char* aD_ = base_ + h_ * 8192 + wid * 2048;                                     \
      char* bD_ = base_ + 16384 + h_ * 8192 + wid * 2048;                             \
      __builtin_amdgcn_global_load_lds(GLOBAL_AS(aSrc + k0_ + h_ * 32), LDS_AS(aD_), 16, 0, 0); \
      __builtin_amdgcn_global_load_lds(GLOBAL_AS(aSrc + k0_ + h_ * 32 + 16 * ND), LDS_AS(aD_ + 1024), 16, 0, 0); \
      __builtin_amdgcn_global_load_lds(GLOBAL_AS(bSrc + k0_ + h_ * 32), LDS_AS(bD_), 16, 0, 0); \
      __builtin_amdgcn_global_load_lds(GLOBAL_AS(bSrc + k0_ + h_ * 32 + 16 * ND), LDS_AS(bD_ + 1024), 16, 0, 0); \
    } } while (0)

  f4_t acc[4][4];
#pragma unroll
  for (int m = 0; m < 4; ++m)
#pragma unroll
    for (int n = 0; n < 4; ++n) acc[m][n] = (f4_t)0.f;

  STAGE64(0, 0);
  asm volatile("s_waitcnt vmcnt(0)" ::: "memory");
  __builtin_amdgcn_s_barrier();

  const int NT64 = ND / 64;   // 16
  for (int t = 0; t < NT64; ++t) {
    if (t + 1 < NT64) STAGE64((t + 1) & 1, t + 1);
    const char* base = smem + (t & 1) * 32768;
#pragma unroll
    for (int h = 0; h < 2; ++h) {
      const char* aRd = base + h * 8192 + (wr * 64 + lo) * 64 + hi * 16;
      const char* bRd = base + 16384 + h * 8192 + (wc * 64 + lo) * 64 + hi * 16;
      bf8_t af[4], bfr[4];
#pragma unroll
      for (int m = 0; m < 4; ++m) af[m] = *reinterpret_cast<const bf8_t*>(aRd + m * 1024);
#pragma unroll
      for (int n = 0; n < 4; ++n) bfr[n] = *reinterpret_cast<const bf8_t*>(bRd + n * 1024);
#pragma unroll
      for (int m = 0; m < 4; ++m)
#pragma unroll
        for (int n = 0; n < 4; ++n)
          acc[m][n] = __builtin_amdgcn_mfma_f32_16x16x32_bf16(af[m], bfr[n], acc[m][n], 0, 0, 0);
    }
    asm volatile("s_waitcnt vmcnt(0)" ::: "memory");
    __builtin_amdgcn_s_barrier();
  }
#undef STAGE64

  dist_epilogue(acc, cnorm, Ep, part, m0, n0, tid, wr, wc, lo, hi, blockIdx.x);
}

// ---------------------------------------------------------------------------
// VB: ZERO-BARRIER register streaming. No LDS staging; each wave loads its
// MFMA A/B fragments straight from global (per-lane 16B, L2/L3-resident) and
// runs the whole K-loop with no __syncthreads / no explicit waitcnt — the
// compiler pipelines loads across unrolled K-steps. LDS only for epilogue.
// ---------------------------------------------------------------------------
__global__ void __launch_bounds__(256)
vq_dist_noba(const unsigned short* __restrict__ xb, const unsigned short* __restrict__ cbb,
             const float* __restrict__ cnorm, Top2* __restrict__ part, int moff) {
  __shared__ Top2 Ep[BM][2];

  const int tid = threadIdx.x, lane = tid & 63, wid = tid >> 6;
  const int wr = wid >> 1, wc = wid & 1, lo = lane & 15, hi = lane >> 4;
  const int m0 = moff + blockIdx.y * BM, n0 = blockIdx.x * BN;

  // per-lane fragment bases: frag layout row = lo, k-elems = kk*32 + hi*8 + [0..7]
  const unsigned short* aRow = xb + (size_t)(m0 + wr * 64 + lo) * ND + hi * 8;
  const unsigned short* bRow = cbb + (size_t)(n0 + wc * 64 + lo) * ND + hi * 8;

  f4_t acc[4][4];
#pragma unroll
  for (int m = 0; m < 4; ++m)
#pragma unroll
    for (int n = 0; n < 4; ++n) acc[m][n] = (f4_t)0.f;

#pragma unroll 4
  for (int kk = 0; kk < ND / 32; ++kk) {
    bf8_t af[4], bfr[4];
#pragma unroll
    for (int m = 0; m < 4; ++m)
      af[m] = *reinterpret_cast<const bf8_t*>(aRow + m * 16 * ND + kk * 32);
#pragma unroll
    for (int n = 0; n < 4; ++n)
      bfr[n] = *reinterpret_cast<const bf8_t*>(bRow + n * 16 * ND + kk * 32);
#pragma unroll
    for (int m = 0; m < 4; ++m)
#pragma unroll
      for (int n = 0; n < 4; ++n)
        acc[m][n] = __builtin_amdgcn_mfma_f32_16x16x32_bf16(af[m], bfr[n], acc[m][n], 0, 0, 0);
  }

  dist_epilogue(acc, cnorm, Ep, part, m0, n0, tid, wr, wc, lo, hi, blockIdx.x);
}

// ---------------------------------------------------------------------------
// Kernel 3: merge partials -> top-4 -> fp64-exact refine -> gather + PE
// ---------------------------------------------------------------------------
__device__ __forceinline__ void ins4(float m, int i, float v[4], int ix[4]) {
  if (!(m < v[3] || (m == v[3] && i < ix[3]))) return;
  v[3] = m; ix[3] = i;
  if (v[3] < v[2] || (v[3] == v[2] && ix[3] < ix[2])) {
    float tv = v[2]; v[2] = v[3]; v[3] = tv; int ti = ix[2]; ix[2] = ix[3]; ix[3] = ti;
  }
  if (v[2] < v[1] || (v[2] == v[1] && ix[2] < ix[1])) {
    float tv = v[1]; v[1] = v[2]; v[2] = tv; int ti = ix[1]; ix[1] = ix[2]; ix[2] = ti;
  }
  if (v[1] < v[0] || (v[1] == v[0] && ix[1] < ix[0])) {
    float tv = v[0]; v[0] = v[1]; v[1] = tv; int ti = ix[0]; ix[0] = ix[1]; ix[1] = ti;
  }
}

__global__ void vq_finalize(const float* __restrict__ x, const float* __restrict__ cb,
                            const Top2* __restrict__ part, float* __restrict__ out) {
  const int t = blockIdx.x;
  const int s = t & (NS - 1);
  const int tid = threadIdx.x;
  const int lane = tid & 63;
  const int wav = tid >> 6;

  __shared__ int candS[4];
  __shared__ double dS[4];
  __shared__ int selS;

  if (wav == 0) {
    float v[4] = {INFINITY, INFINITY, INFINITY, INFINITY};
    int ix[4] = {0x7fffffff, 0x7fffffff, 0x7fffffff, 0x7fffffff};
    if (lane < NTILES) {
      Top2 e = part[(size_t)t * NTILES + lane];
      v[0] = e.m1; ix[0] = e.i1; v[1] = e.m2; ix[1] = e.i2;
    }
#pragma unroll
    for (int mask = 1; mask <= 16; mask <<= 1) {
      float ov[4]; int oi[4];
#pragma unroll
      for (int p = 0; p < 4; ++p) { ov[p] = __shfl_xor(v[p], mask, 64); oi[p] = __shfl_xor(ix[p], mask, 64); }
#pragma unroll
      for (int p = 0; p < 4; ++p) ins4(ov[p], oi[p], v, ix);
    }
    if (lane < 4) candS[lane] = ix[lane];
  }
  __syncthreads();

  const int ci = candS[wav];
  const float* xt = x + (size_t)t * ND;
  const float* c = cb + (size_t)ci * ND;
  double d = 0.0;
#pragma unroll
  for (int r = 0; r < ND / 64; ++r) {
    int j = lane + 64 * r;
    double a = (double)xt[j] - (double)c[j];
    d = fma(a, a, d);
  }
#pragma unroll
  for (int off = 32; off > 0; off >>= 1) d += __shfl_down(d, off, 64);
  if (lane == 0) dS[wav] = d;
  __syncthreads();

  if (tid == 0) {
    double bd = dS[0]; int bi = candS[0];
#pragma unroll
    for (int w = 1; w < 4; ++w) {
      if (dS[w] < bd || (dS[w] == bd && candS[w] < bi)) { bd = dS[w]; bi = candS[w]; }
    }
    selS = bi;
  }
  __syncthreads();
  const int sel = selS;

  const float coef = (float)(9.210340371976184 / 1024.0);
  const float* cs = cb + (size_t)sel * ND;
  float* ot = out + (size_t)t * ND;
  const float sf = (float)s;
#pragma unroll
  for (int r = 0; r < ND / 256; ++r) {
    int j = tid + 256 * r;
    int iv = j & ~1;
    float div = expf(-(float)iv * coef);
    float ang = sf * div;
    float pe = (j & 1) ? cosf(ang) : sinf(ang);
    ot[j] = cs[j] + pe;
  }
}

// ---------------------------------------------------------------------------
extern "C" void kernel_launch(void* const* d_in, const int* in_sizes, int n_in,
                              void* d_out, int out_size, void* d_ws, size_t ws_size,
                              hipStream_t stream) {
  const float* x = (const float*)d_in[0];
  const float* cb = (const float*)d_in[1];
  float* out = (float*)d_out;

  unsigned short* xb = (unsigned short*)d_ws;
  unsigned short* cbb = (unsigned short*)((char*)d_ws + (size_t)NM * ND * 2);
  float* cnorm = (float*)((char*)d_ws + (size_t)NM * ND * 2 + (size_t)NK * ND * 2);
  Top2* part = (Top2*)((char*)cnorm + 16384);

  vq_convert<<<2048, 256, 0, stream>>>(x, cb, xb, cbb);
  vq_cnorm<<<NK / 4, 256, 0, stream>>>(cb, cnorm);

  // 2-way ablation: half the tokens each
  dim3 g(NTILES, NM / BM / 2);  // (32, 64)
  vq_dist_bk64<<<g, 256, 0, stream>>>(xb, cbb, cnorm, part, 0);      // VA: fat steps
  vq_dist_noba<<<g, 256, 0, stream>>>(xb, cbb, cnorm, part, 8192);   // VB: zero-barrier

  vq_finalize<<<NM, 256, 0, stream>>>(x, cb, part, out);
}